// Round 7
// baseline (65.643 us; speedup 1.0000x reference)
//
#include <hip/hip_runtime.h>

#define I_FEAT 8192
#define O_FEAT 8192
#define BATCH  1024

// K1 geometry: 2048-col x 16-row panels -> 4 col-chunks x 512 splits = 2048
// blocks = 8 blocks/CU (32 waves/CU), wide panels + 16 loads in flight/thread.
#define NS        512
#define ROWS_PB   16
#define CCHUNKS   4
#define SGROUPS   8
#define SPLITS_PER_GROUP (NS / SGROUPS)  // 64

using f4 = __attribute__((ext_vector_type(4))) float;

// ---------------- K1: partial column sums of W ----------------
__global__ __launch_bounds__(256) void colsum_partial_kernel(
    const float* __restrict__ W, float* __restrict__ partials) {
  const int chunk = blockIdx.x & (CCHUNKS - 1);
  const int split = blockIdx.x / CCHUNKS;
  const int t = threadIdx.x;
  const int c = (chunk << 11) + (t << 2);  // chunk*2048 + t*4

  const float* base = W + (size_t)split * ROWS_PB * I_FEAT + c;

  // 4 rotating slots x 2 column-groups; unroll 8 -> 16 independent loads in flight
  f4 acc[4][2];
#pragma unroll
  for (int s = 0; s < 4; ++s) { acc[s][0] = (f4)(0.f); acc[s][1] = (f4)(0.f); }

#pragma unroll 8
  for (int r = 0; r < ROWS_PB; ++r) {
    const float* rp = base + (size_t)r * I_FEAT;
    acc[r & 3][0] += *(const f4*)(rp);
    acc[r & 3][1] += *(const f4*)(rp + 1024);
  }

  f4 s0 = (acc[0][0] + acc[1][0]) + (acc[2][0] + acc[3][0]);
  f4 s1 = (acc[0][1] + acc[1][1]) + (acc[2][1] + acc[3][1]);
  float* o = partials + (size_t)split * I_FEAT + c;
  *(f4*)o = s0;
  *(f4*)(o + 1024) = s1;
}

// ------- K2a: partials[512] -> p2[8] per 1024-col slice; block 64: bsum ----
__global__ __launch_bounds__(256) void reduce1_kernel(
    const float* __restrict__ partials, const float* __restrict__ b,
    float* __restrict__ p2, float* __restrict__ bsum) {
  __shared__ float red[4];
  const int t = threadIdx.x;
  if (blockIdx.x < 64) {
    const int cb = blockIdx.x & 7;
    const int sg = blockIdx.x >> 3;
    const int c  = (cb << 10) + (t << 2);
    const float* base = partials + (size_t)sg * SPLITS_PER_GROUP * I_FEAT + c;
    f4 s = (f4)(0.f);
#pragma unroll 8
    for (int sp = 0; sp < SPLITS_PER_GROUP; ++sp)  // 64 iters
      s += *(const f4*)(base + (size_t)sp * I_FEAT);
    *(f4*)(p2 + (size_t)sg * I_FEAT + c) = s;
  } else {
    float s = 0.f;
    const f4* b4 = (const f4*)b;
    for (int j = t; j < O_FEAT / 4; j += 256) {
      f4 v = b4[j];
      s += (v.x + v.y) + (v.z + v.w);
    }
#pragma unroll
    for (int off = 32; off; off >>= 1) s += __shfl_down(s, off);
    if ((t & 63) == 0) red[t >> 6] = s;
    __syncthreads();
    if (t == 0) bsum[0] = (red[0] + red[1]) + (red[2] + red[3]);
  }
}

// ---------------- K2b: p2[8] -> colsum ----------------
__global__ __launch_bounds__(256) void reduce2_kernel(
    const float* __restrict__ p2, float* __restrict__ colsum) {
  const int c = (blockIdx.x << 10) + (threadIdx.x << 2);
  f4 s = (f4)(0.f);
#pragma unroll
  for (int g = 0; g < SGROUPS; ++g)
    s += *(const f4*)(p2 + (size_t)g * I_FEAT + c);
  *(f4*)(colsum + c) = s;
}

// ---------------- K3: out[row] = dot(x[row], colsum) + bsum ----------------
__global__ __launch_bounds__(256) void rowdot_kernel(
    const float* __restrict__ x, const float* __restrict__ colsum,
    const float* __restrict__ bsum, float* __restrict__ out) {
  __shared__ float red[4];
  const int row = blockIdx.x;
  const int t = threadIdx.x;
  const f4* xr = (const f4*)(x + (size_t)row * I_FEAT);
  const f4* cs = (const f4*)colsum;

  float s = 0.f;
#pragma unroll
  for (int j = 0; j < 8; ++j) {
    const int idx = t + j * 256;
    f4 a = xr[idx];
    f4 c = cs[idx];
    s += a.x * c.x + a.y * c.y + a.z * c.z + a.w * c.w;
  }
#pragma unroll
  for (int off = 32; off; off >>= 1) s += __shfl_down(s, off);
  if ((t & 63) == 0) red[t >> 6] = s;
  __syncthreads();
  if (t == 0)
    out[row] = (red[0] + red[1]) + (red[2] + red[3]) + bsum[0];
}

extern "C" void kernel_launch(void* const* d_in, const int* in_sizes, int n_in,
                              void* d_out, int out_size, void* d_ws, size_t ws_size,
                              hipStream_t stream) {
  const float* x = (const float*)d_in[0];  // (1024, 8192)
  const float* W = (const float*)d_in[1];  // (8192, 8192)
  const float* b = (const float*)d_in[2];  // (8192,)
  float* out = (float*)d_out;              // (1024,)

  // ws: partials [512][8192] f32 (16MB) | p2 [8][8192] (256KB) | colsum | bsum
  float* partials = (float*)d_ws;
  float* p2       = partials + (size_t)NS * I_FEAT;
  float* colsum   = p2 + (size_t)SGROUPS * I_FEAT;
  float* bsum     = colsum + I_FEAT;

  colsum_partial_kernel<<<NS * CCHUNKS, 256, 0, stream>>>(W, partials);
  reduce1_kernel<<<65, 256, 0, stream>>>(partials, b, p2, bsum);
  reduce2_kernel<<<8, 256, 0, stream>>>(p2, colsum);
  rowdot_kernel<<<BATCH, 256, 0, stream>>>(x, colsum, bsum, out);
}

// Round 8
// 65.507 us; speedup vs baseline: 1.0021x; 1.0021x over previous
//
#include <hip/hip_runtime.h>

#define I_FEAT 8192
#define O_FEAT 8192
#define BATCH  1024

// K1 geometry (R3 optimum): 2048-col x 32-row panels -> 4 chunks x 256 splits
// = 1024 blocks = 4 blocks/CU (16 waves/CU), 16 loads in flight per thread.
#define NS        256
#define ROWS_PB   32
#define CCHUNKS   4
#define SGROUPS   8
#define SPLITS_PER_GROUP (NS / SGROUPS)  // 32

using f4 = __attribute__((ext_vector_type(4))) float;

// ---------------- K1: partial column sums of W ----------------
__global__ __launch_bounds__(256) void colsum_partial_kernel(
    const float* __restrict__ W, float* __restrict__ partials,
    unsigned int* __restrict__ cnt) {
  // Zero the K2 arrival counters once per launch (stream-ordered before K2).
  if (blockIdx.x == 0 && threadIdx.x < CCHUNKS * 2) cnt[threadIdx.x] = 0;

  const int chunk = blockIdx.x & (CCHUNKS - 1);
  const int split = blockIdx.x / CCHUNKS;
  const int t = threadIdx.x;
  const int c = (chunk << 11) + (t << 2);  // chunk*2048 + t*4

  const float* base = W + (size_t)split * ROWS_PB * I_FEAT + c;

  // 4 rotating slots x 2 column-groups; unroll 8 -> 16 independent loads in flight
  f4 acc[4][2];
#pragma unroll
  for (int s = 0; s < 4; ++s) { acc[s][0] = (f4)(0.f); acc[s][1] = (f4)(0.f); }

#pragma unroll 8
  for (int r = 0; r < ROWS_PB; ++r) {
    const float* rp = base + (size_t)r * I_FEAT;
    acc[r & 3][0] += *(const f4*)(rp);
    acc[r & 3][1] += *(const f4*)(rp + 1024);
  }

  f4 s0 = (acc[0][0] + acc[1][0]) + (acc[2][0] + acc[3][0]);
  f4 s1 = (acc[0][1] + acc[1][1]) + (acc[2][1] + acc[3][1]);
  float* o = partials + (size_t)split * I_FEAT + c;
  *(f4*)o = s0;
  *(f4*)(o + 1024) = s1;
}

// ---- K2 (fused): 64 blocks partials->p2, last-arrival per col-chunk sums
//      p2 -> colsum in FIXED order (deterministic); block 64 reduces b -> bsum.
__global__ __launch_bounds__(256) void reduce_kernel(
    const float* __restrict__ partials, const float* __restrict__ b,
    float* __restrict__ p2, float* __restrict__ colsum,
    float* __restrict__ bsum, unsigned int* __restrict__ cnt) {
  __shared__ float red[4];
  __shared__ int isfin;
  const int t = threadIdx.x;
  if (blockIdx.x < 64) {
    const int cb = blockIdx.x & 7;   // 8 x 1024-col slices
    const int sg = blockIdx.x >> 3;  // 8 split-groups
    const int c  = (cb << 10) + (t << 2);
    const float* base = partials + (size_t)sg * SPLITS_PER_GROUP * I_FEAT + c;
    f4 s = (f4)(0.f);
#pragma unroll 8
    for (int sp = 0; sp < SPLITS_PER_GROUP; ++sp)  // 32 iters
      s += *(const f4*)(base + (size_t)sp * I_FEAT);
    *(f4*)(p2 + (size_t)sg * I_FEAT + c) = s;

    __threadfence();  // release p2 write (device scope)
    if (t == 0) {
      unsigned int r = atomicAdd(&cnt[cb], 1u);  // device-scope
      isfin = (r == SGROUPS - 1);
    }
    __syncthreads();
    if (isfin) {
      __threadfence();  // acquire other blocks' p2 writes
      f4 s2 = (f4)(0.f);
#pragma unroll
      for (int g = 0; g < SGROUPS; ++g)  // fixed order -> bit-exact
        s2 += *(const f4*)(p2 + (size_t)g * I_FEAT + c);
      *(f4*)(colsum + c) = s2;
    }
  } else {
    float s = 0.f;
    const f4* b4 = (const f4*)b;
    for (int j = t; j < O_FEAT / 4; j += 256) {
      f4 v = b4[j];
      s += (v.x + v.y) + (v.z + v.w);
    }
#pragma unroll
    for (int off = 32; off; off >>= 1) s += __shfl_down(s, off);
    if ((t & 63) == 0) red[t >> 6] = s;
    __syncthreads();
    if (t == 0) bsum[0] = (red[0] + red[1]) + (red[2] + red[3]);
  }
}

// ---------------- K3: out[row] = dot(x[row], colsum) + bsum ----------------
__global__ __launch_bounds__(256) void rowdot_kernel(
    const float* __restrict__ x, const float* __restrict__ colsum,
    const float* __restrict__ bsum, float* __restrict__ out) {
  __shared__ float red[4];
  const int row = blockIdx.x;
  const int t = threadIdx.x;
  const f4* xr = (const f4*)(x + (size_t)row * I_FEAT);
  const f4* cs = (const f4*)colsum;

  float s = 0.f;
#pragma unroll
  for (int j = 0; j < 8; ++j) {
    const int idx = t + j * 256;
    f4 a = xr[idx];
    f4 c = cs[idx];
    s += a.x * c.x + a.y * c.y + a.z * c.z + a.w * c.w;
  }
#pragma unroll
  for (int off = 32; off; off >>= 1) s += __shfl_down(s, off);
  if ((t & 63) == 0) red[t >> 6] = s;
  __syncthreads();
  if (t == 0)
    out[row] = (red[0] + red[1]) + (red[2] + red[3]) + bsum[0];
}

extern "C" void kernel_launch(void* const* d_in, const int* in_sizes, int n_in,
                              void* d_out, int out_size, void* d_ws, size_t ws_size,
                              hipStream_t stream) {
  const float* x = (const float*)d_in[0];  // (1024, 8192)
  const float* W = (const float*)d_in[1];  // (8192, 8192)
  const float* b = (const float*)d_in[2];  // (8192,)
  float* out = (float*)d_out;              // (1024,)

  // ws: partials [256][8192] f32 (8MB) | p2 [8][8192] (256KB) | colsum [8192]
  //     | bsum [1] | cnt [8] u32
  float* partials = (float*)d_ws;
  float* p2       = partials + (size_t)NS * I_FEAT;
  float* colsum   = p2 + (size_t)SGROUPS * I_FEAT;
  float* bsum     = colsum + I_FEAT;
  unsigned int* cnt = (unsigned int*)(bsum + 4);

  colsum_partial_kernel<<<NS * CCHUNKS, 256, 0, stream>>>(W, partials, cnt);
  reduce_kernel<<<65, 256, 0, stream>>>(partials, b, p2, colsum, bsum, cnt);
  rowdot_kernel<<<BATCH, 256, 0, stream>>>(x, colsum, bsum, out);
}

// Round 9
// 61.417 us; speedup vs baseline: 1.0688x; 1.0666x over previous
//
#include <hip/hip_runtime.h>

#define I_FEAT 8192
#define O_FEAT 8192
#define BATCH  1024

// K1 geometry (R3 optimum): 2048-col x 32-row panels -> 4 chunks x 256 splits
// = 1024 blocks = 4 blocks/CU (16 waves/CU), 16 loads in flight per thread.
#define NS        256
#define ROWS_PB   32
#define CCHUNKS   4
#define SGROUPS   8
#define SPLITS_PER_GROUP (NS / SGROUPS)  // 32

using f4 = __attribute__((ext_vector_type(4))) float;

// ---------------- K1: partial column sums of W ----------------
// Scratch (partials) is written nontemporal ('nt', evict-first) so it does
// not evict the L3-resident portion of W between graph replays.
__global__ __launch_bounds__(256) void colsum_partial_kernel(
    const float* __restrict__ W, float* __restrict__ partials) {
  const int chunk = blockIdx.x & (CCHUNKS - 1);
  const int split = blockIdx.x / CCHUNKS;
  const int t = threadIdx.x;
  const int c = (chunk << 11) + (t << 2);  // chunk*2048 + t*4

  const float* base = W + (size_t)split * ROWS_PB * I_FEAT + c;

  // 4 rotating slots x 2 column-groups; unroll 8 -> 16 independent loads in flight
  f4 acc[4][2];
#pragma unroll
  for (int s = 0; s < 4; ++s) { acc[s][0] = (f4)(0.f); acc[s][1] = (f4)(0.f); }

#pragma unroll 8
  for (int r = 0; r < ROWS_PB; ++r) {
    const float* rp = base + (size_t)r * I_FEAT;
    acc[r & 3][0] += *(const f4*)(rp);
    acc[r & 3][1] += *(const f4*)(rp + 1024);
  }

  f4 s0 = (acc[0][0] + acc[1][0]) + (acc[2][0] + acc[3][0]);
  f4 s1 = (acc[0][1] + acc[1][1]) + (acc[2][1] + acc[3][1]);
  float* o = partials + (size_t)split * I_FEAT + c;
  __builtin_nontemporal_store(s0, (f4*)o);
  __builtin_nontemporal_store(s1, (f4*)(o + 1024));
}

// ------- K2a: partials[256] -> p2[8] per 1024-col slice; block 64: bsum ----
__global__ __launch_bounds__(256) void reduce1_kernel(
    const float* __restrict__ partials, const float* __restrict__ b,
    float* __restrict__ p2, float* __restrict__ bsum) {
  __shared__ float red[4];
  const int t = threadIdx.x;
  if (blockIdx.x < 64) {
    const int cb = blockIdx.x & 7;
    const int sg = blockIdx.x >> 3;
    const int c  = (cb << 10) + (t << 2);
    const float* base = partials + (size_t)sg * SPLITS_PER_GROUP * I_FEAT + c;
    f4 s = (f4)(0.f);
#pragma unroll 8
    for (int sp = 0; sp < SPLITS_PER_GROUP; ++sp)  // 32 iters
      s += __builtin_nontemporal_load((const f4*)(base + (size_t)sp * I_FEAT));
    __builtin_nontemporal_store(s, (f4*)(p2 + (size_t)sg * I_FEAT + c));
  } else {
    float s = 0.f;
    const f4* b4 = (const f4*)b;
    for (int j = t; j < O_FEAT / 4; j += 256) {
      f4 v = b4[j];
      s += (v.x + v.y) + (v.z + v.w);
    }
#pragma unroll
    for (int off = 32; off; off >>= 1) s += __shfl_down(s, off);
    if ((t & 63) == 0) red[t >> 6] = s;
    __syncthreads();
    if (t == 0) bsum[0] = (red[0] + red[1]) + (red[2] + red[3]);
  }
}

// ---------------- K2b: p2[8] -> colsum ----------------
__global__ __launch_bounds__(256) void reduce2_kernel(
    const float* __restrict__ p2, float* __restrict__ colsum) {
  const int c = (blockIdx.x << 10) + (threadIdx.x << 2);
  f4 s = (f4)(0.f);
#pragma unroll
  for (int g = 0; g < SGROUPS; ++g)
    s += __builtin_nontemporal_load((const f4*)(p2 + (size_t)g * I_FEAT + c));
  *(f4*)(colsum + c) = s;
}

// ---------------- K3: out[row] = dot(x[row], colsum) + bsum ----------------
__global__ __launch_bounds__(256) void rowdot_kernel(
    const float* __restrict__ x, const float* __restrict__ colsum,
    const float* __restrict__ bsum, float* __restrict__ out) {
  __shared__ float red[4];
  const int row = blockIdx.x;
  const int t = threadIdx.x;
  const f4* xr = (const f4*)(x + (size_t)row * I_FEAT);
  const f4* cs = (const f4*)colsum;

  float s = 0.f;
#pragma unroll
  for (int j = 0; j < 8; ++j) {
    const int idx = t + j * 256;
    f4 a = xr[idx];
    f4 c = cs[idx];
    s += a.x * c.x + a.y * c.y + a.z * c.z + a.w * c.w;
  }
#pragma unroll
  for (int off = 32; off; off >>= 1) s += __shfl_down(s, off);
  if ((t & 63) == 0) red[t >> 6] = s;
  __syncthreads();
  if (t == 0)
    out[row] = (red[0] + red[1]) + (red[2] + red[3]) + bsum[0];
}

extern "C" void kernel_launch(void* const* d_in, const int* in_sizes, int n_in,
                              void* d_out, int out_size, void* d_ws, size_t ws_size,
                              hipStream_t stream) {
  const float* x = (const float*)d_in[0];  // (1024, 8192)
  const float* W = (const float*)d_in[1];  // (8192, 8192)
  const float* b = (const float*)d_in[2];  // (8192,)
  float* out = (float*)d_out;              // (1024,)

  // ws: partials [256][8192] f32 (8MB) | p2 [8][8192] (256KB) | colsum | bsum
  float* partials = (float*)d_ws;
  float* p2       = partials + (size_t)NS * I_FEAT;
  float* colsum   = p2 + (size_t)SGROUPS * I_FEAT;
  float* bsum     = colsum + I_FEAT;

  colsum_partial_kernel<<<NS * CCHUNKS, 256, 0, stream>>>(W, partials);
  reduce1_kernel<<<65, 256, 0, stream>>>(partials, b, p2, bsum);
  reduce2_kernel<<<8, 256, 0, stream>>>(p2, colsum);
  rowdot_kernel<<<BATCH, 256, 0, stream>>>(x, colsum, bsum, out);
}